// Round 4
// baseline (157.357 us; speedup 1.0000x reference)
//
#include <hip/hip_runtime.h>

// Problem constants (match reference setup_inputs):
//   B=32, N=3072, F=256, P=3, S=N/P=1024
// out shape (B, S, F, 1) -> flat B*S*F floats.
constexpr int Bdim = 32;
constexpr int Ndim = 3072;
constexpr int Fdim = 256;
constexpr int Pdim = 3;
constexpr int Sdim = Ndim / Pdim;   // 1024
constexpr int WAVES_PER_BLOCK = 4;  // 256 threads
constexpr int WIN_PER_WAVE = 4;     // pipelined windows per wave

// Native vector type for __builtin_nontemporal_store (HIP float4 is a class).
typedef float vfloat4 __attribute__((ext_vector_type(4)));

// Full 64-lane sum via DPP (VALU-only, no LDS pipe):
//   row_shr:1,2,4,8 -> inclusive prefix within each 16-lane row
//   row_bcast:15, row_bcast:31 -> combine row sums into lane 63
//   readlane(63) broadcasts the total to all lanes via SGPR.
__device__ __forceinline__ float wave_allsum(float v) {
    float t = v;
    int x;
    x = __builtin_amdgcn_update_dpp(0, __float_as_int(t), 0x111, 0xF, 0xF, true); // row_shr:1
    t += __int_as_float(x);
    x = __builtin_amdgcn_update_dpp(0, __float_as_int(t), 0x112, 0xF, 0xF, true); // row_shr:2
    t += __int_as_float(x);
    x = __builtin_amdgcn_update_dpp(0, __float_as_int(t), 0x114, 0xF, 0xF, true); // row_shr:4
    t += __int_as_float(x);
    x = __builtin_amdgcn_update_dpp(0, __float_as_int(t), 0x118, 0xF, 0xF, true); // row_shr:8
    t += __int_as_float(x);
    x = __builtin_amdgcn_update_dpp(0, __float_as_int(t), 0x142, 0xF, 0xF, true); // row_bcast:15
    t += __int_as_float(x);
    x = __builtin_amdgcn_update_dpp(0, __float_as_int(t), 0x143, 0xF, 0xF, true); // row_bcast:31
    t += __int_as_float(x);
    return __int_as_float(__builtin_amdgcn_readlane(__float_as_int(t), 63));
}

// One 64-lane wave handles WIN_PER_WAVE consecutive windows, software-pipelined:
// loads for window k+1 are issued before the reduce/softmax of window k, so the
// cross-lane chain latency overlaps memory. Lane i owns float4 at f = 4*i.
__global__ __launch_bounds__(256) void gap_kernel(
    const float* __restrict__ x,   // [B, N, F]
    const float* __restrict__ w,   // [F]
    float* __restrict__ out)       // [B, S, F]
{
    const int lane = threadIdx.x & 63;
    const int wave = threadIdx.x >> 6;
    const int wid  = blockIdx.x * WAVES_PER_BLOCK + wave;
    const int win0 = wid * WIN_PER_WAVE;

    const vfloat4 w4 = *(const vfloat4*)(w + lane * 4);

    const size_t base = (size_t)win0 * (Pdim * Fdim) + lane * 4;
    vfloat4 a0 = *(const vfloat4*)(x + base);
    vfloat4 a1 = *(const vfloat4*)(x + base + Fdim);
    vfloat4 a2 = *(const vfloat4*)(x + base + 2 * Fdim);

    #pragma unroll
    for (int k = 0; k < WIN_PER_WAVE; ++k) {
        vfloat4 b0 = a0, b1 = a1, b2 = a2;
        if (k + 1 < WIN_PER_WAVE) {
            const size_t nb = base + (size_t)(k + 1) * (Pdim * Fdim);
            b0 = *(const vfloat4*)(x + nb);
            b1 = *(const vfloat4*)(x + nb + Fdim);
            b2 = *(const vfloat4*)(x + nb + 2 * Fdim);
        }

        float p0 = a0.x * w4.x + a0.y * w4.y + a0.z * w4.z + a0.w * w4.w;
        float p1 = a1.x * w4.x + a1.y * w4.y + a1.z * w4.z + a1.w * w4.w;
        float p2 = a2.x * w4.x + a2.y * w4.y + a2.z * w4.z + a2.w * w4.w;

        const float d0 = wave_allsum(p0);
        const float d1 = wave_allsum(p1);
        const float d2 = wave_allsum(p2);

        // Softmax over the 3 scores (bias is uniform -> cancels in softmax).
        const float m  = fmaxf(d0, fmaxf(d1, d2));
        float e0 = __expf(d0 - m);
        float e1 = __expf(d1 - m);
        float e2 = __expf(d2 - m);
        const float inv = 1.0f / (e0 + e1 + e2);
        e0 *= inv; e1 *= inv; e2 *= inv;

        vfloat4 o;
        o.x = a0.x * e0 + a1.x * e1 + a2.x * e2;
        o.y = a0.y * e0 + a1.y * e1 + a2.y * e2;
        o.z = a0.z * e0 + a1.z * e1 + a2.z * e2;
        o.w = a0.w * e0 + a1.w * e1 + a2.w * e2;

        // Nontemporal: don't let the 34 MB output evict L3-resident x.
        __builtin_nontemporal_store(o, (vfloat4*)(out + (size_t)(win0 + k) * Fdim + lane * 4));

        a0 = b0; a1 = b1; a2 = b2;
    }
}

extern "C" void kernel_launch(void* const* d_in, const int* in_sizes, int n_in,
                              void* d_out, int out_size, void* d_ws, size_t ws_size,
                              hipStream_t stream) {
    const float* x = (const float*)d_in[0];   // [B, N, F] fp32
    const float* w = (const float*)d_in[1];   // [F] fp32
    // d_in[2] = W_bias — uniform additive constant, cancels in softmax.
    float* out = (float*)d_out;               // [B, S, F, 1] fp32

    const int n_windows = Bdim * Sdim;                              // 32768
    const int grid = n_windows / (WAVES_PER_BLOCK * WIN_PER_WAVE);  // 2048
    gap_kernel<<<grid, WAVES_PER_BLOCK * 64, 0, stream>>>(x, w, out);
}